// Round 4
// baseline (1662.038 us; speedup 1.0000x reference)
//
#include <hip/hip_runtime.h>
#include <cstdint>
#include <cstddef>

// Problem constants (fixed by the reference).
constexpr int Bn = 2048, Ln = 128, Cn = 32, Hn = 64, On = 16;
constexpr int NIv = Ln - 1;                       // 127 intervals
constexpr float K2 = 2.885390081777927f;          // 2*log2(e): tanh(x)=1-2/(1+exp2(K2*x))
constexpr float TSCL = 128.0f;                    // LUT: 2048 entries over [-8, 8]
constexpr float TBIAS = 1024.0f;
constexpr float THI = 2046.99f;                   // clamp for index+frac

__device__ __forceinline__ float fexp2(float x) {
#if __has_builtin(__builtin_amdgcn_exp2f)
  return __builtin_amdgcn_exp2f(x);
#else
  float r; asm("v_exp_f32 %0, %1" : "=v"(r) : "v"(x)); return r;
#endif
}
__device__ __forceinline__ float frcpf(float x) {
#if __has_builtin(__builtin_amdgcn_rcpf)
  return __builtin_amdgcn_rcpf(x);
#else
  float r; asm("v_rcp_f32 %0, %1" : "=v"(r) : "v"(x)); return r;
#endif
}
__device__ __forceinline__ float tanh_fast(float x) {   // exact-ish; table build + z output
  float e = fexp2(K2 * x);
  return fmaf(-2.0f, frcpf(e + 1.0f), 1.0f);
}
__device__ __forceinline__ float ffract(float x) {
  float r; asm("v_fract_f32 %0, %1" : "=v"(r) : "v"(x)); return r;
}

// One DPP add step of a butterfly reduce (full-rate VALU, no LDS).
template<int CTRL>
__device__ __forceinline__ float dpp_addstep(float p) {
  int q = __builtin_amdgcn_update_dpp(0, __float_as_int(p), CTRL, 0xF, 0xF, true);
  return p + __int_as_float(q);
}
// After these 4 steps every 16-lane row holds its row-sum in all lanes.
__device__ __forceinline__ float dpp_rowsum16(float p) {
  p = dpp_addstep<0xB1>(p);    // quad_perm [1,0,3,2]  (xor1)
  p = dpp_addstep<0x4E>(p);    // quad_perm [2,3,0,1]  (xor2)
  p = dpp_addstep<0x141>(p);   // row_half_mirror      (xor4..7)
  p = dpp_addstep<0x140>(p);   // row_mirror           (xor8..15)
  return p;
}
__device__ __forceinline__ float lane4_total(float p) {
  float s0 = __int_as_float(__builtin_amdgcn_readlane(__float_as_int(p), 0));
  float s1 = __int_as_float(__builtin_amdgcn_readlane(__float_as_int(p), 16));
  float s2 = __int_as_float(__builtin_amdgcn_readlane(__float_as_int(p), 32));
  float s3 = __int_as_float(__builtin_amdgcn_readlane(__float_as_int(p), 48));
  return (s0 + s1) + (s2 + s3);
}

// ---------------------------------------------------------------------------
// Kernel 1: sequential RK4 scan. One wave64 per batch element; lane = h.
// tanh inner nonlinearity via LDS LUT (linear interp): per element 8 VALU ops
// + 1 ds_read_b64 on the LDS pipe (trans ops eliminated from the hot loop).
// Weights held as NAMED scalar floats (A=128*w20, B=128*w21, C=128*b2+1024).
// ---------------------------------------------------------------------------
#define REP8(M) M(0) M(1) M(2) M(3) M(4) M(5) M(6) M(7)

__global__ __launch_bounds__(256, 2) void ncde_scan_kernel(
    const float* __restrict__ coeffs, const float* __restrict__ t,
    const float* __restrict__ W_init, const float* __restrict__ b_init,
    const float* __restrict__ W1, const float* __restrict__ b1,
    const float* __restrict__ W2, const float* __restrict__ b2,
    float* __restrict__ zt)
{
  __shared__ float2 stab[2048];       // tanh LUT: (y_i, y_{i+1}-y_i), x=(i-1024)/128
  __shared__ float sdx[4][5][32];     // [wave][s-index][c]
  const int wv = threadIdx.x >> 6;
  const int lane = threadIdx.x & 63;
  const int b = (blockIdx.x << 2) | wv;
  float* const sdxw = &sdx[wv][0][0];

  // Build the tanh table (256 threads, 8 entries each).
  for (int i2 = threadIdx.x; i2 < 2048; i2 += 256) {
    const float x0 = ((float)i2 - TBIAS) * (1.0f / TSCL);
    const float y0 = tanh_fast(x0);
    const float y1 = tanh_fast(x0 + (1.0f / TSCL));
    stab[i2] = make_float2(y0, y1 - y0);
  }

  // Per-lane weights. W1 (H,2); W2 (2, H*C); lane h owns W2[:, h*32 .. h*32+31].
  const float w10 = W1[2 * lane], w11 = W1[2 * lane + 1];
  const float sb0 = b1[0], sb1 = b1[1];

#define DECLW(g) float A##g##x, A##g##y, A##g##z, A##g##w, \
                       Bq##g##x, Bq##g##y, Bq##g##z, Bq##g##w, \
                       Cc##g##x, Cc##g##y, Cc##g##z, Cc##g##w;
  REP8(DECLW)
  {
    const float* W2a = W2 + lane * 32;
    const float* W2b = W2 + 2048 + lane * 32;
    const float* b2a = b2 + lane * 32;
#define LOADW(g) { \
      const float4 x0 = *(const float4*)(W2a + 4 * (g)); \
      const float4 x1 = *(const float4*)(W2b + 4 * (g)); \
      const float4 x2 = *(const float4*)(b2a + 4 * (g)); \
      A##g##x = x0.x * TSCL; A##g##y = x0.y * TSCL; A##g##z = x0.z * TSCL; A##g##w = x0.w * TSCL; \
      Bq##g##x = x1.x * TSCL; Bq##g##y = x1.y * TSCL; Bq##g##z = x1.z * TSCL; Bq##g##w = x1.w * TSCL; \
      Cc##g##x = fmaf(x2.x, TSCL, TBIAS); Cc##g##y = fmaf(x2.y, TSCL, TBIAS); \
      Cc##g##z = fmaf(x2.z, TSCL, TBIAS); Cc##g##w = fmaf(x2.w, TSCL, TBIAS); }
    REP8(LOADW)
  }

  // z0 = X0 @ W_init + b_init, X0 = a-part of interval 0.
  const float* cb0 = coeffs + (size_t)b * NIv * 128;
  if (lane < 32) sdxw[lane] = cb0[lane];
  __syncthreads();                    // covers table build + z0 staging
  float z = b_init[lane];
#pragma unroll 4
  for (int c = 0; c < 32; ++c)
    z = fmaf(sdxw[c], W_init[(c << 6) + lane], z);
  zt[(size_t)b * Ln * Hn + lane] = tanh_fast(z);

#pragma unroll 1
  for (int i = 0; i < NIv; ++i) {
    const float* cb = cb0 + (size_t)i * 128;
    const float dti = t[i + 1] - t[i];
    const float hst = 0.5f * dti;
    // Precompute the 5 distinct dXdt vectors (s = 0, .25, .5, .75, 1 times dti).
    __builtin_amdgcn_wave_barrier();
    if (lane < 32) {
      const float bi = cb[32 + lane];
      const float ci = cb[64 + lane];
      const float di = cb[96 + lane];
      const float q = 0.25f * dti;
#pragma unroll
      for (int k = 0; k < 5; ++k) {
        const float s = q * (float)k;
        sdxw[k * 32 + lane] = fmaf(fmaf(di, s, ci), s, bi);
      }
    }
    __builtin_amdgcn_wave_barrier();

    float kacc = 0.0f, kprev = 0.0f;
#pragma unroll
    for (int j = 0; j < 2; ++j) {          // N_SUB substeps
      if (j == 1) { z = fmaf(hst * (1.0f / 6.0f), kacc, z); kacc = 0.0f; kprev = 0.0f; }
#pragma unroll
      for (int st = 0; st < 4; ++st) {     // RK4 stages
        const float cin = (st == 0) ? 0.0f : (st == 3) ? hst : 0.5f * hst;
        const float wgt = (st == 1 || st == 2) ? 2.0f : 1.0f;
        const int kidx = 2 * j + ((st + 1) >> 1);          // compile-time 0..4
        const float* dx = sdxw + kidx * 32;
        const float zs = fmaf(cin, kprev, z);
        // h1 = relu(zs @ W1 + b1): DPP butterfly, two interleaved chains.
        float p0 = dpp_rowsum16(zs * w10);
        float p1 = dpp_rowsum16(zs * w11);
        const float h10 = fmaxf(lane4_total(p0) + sb0, 0.0f);
        const float h11 = fmaxf(lane4_total(p1) + sb1, 0.0f);
        float a0 = 0.0f, a1 = 0.0f, a2 = 0.0f, a3 = 0.0f;
#define GRP(g) { \
        const float4 d4 = *(const float4*)(dx + 4 * (g)); \
        float u0 = fmaf(A##g##x, h10, fmaf(Bq##g##x, h11, Cc##g##x)); \
        float u1 = fmaf(A##g##y, h10, fmaf(Bq##g##y, h11, Cc##g##y)); \
        float u2 = fmaf(A##g##z, h10, fmaf(Bq##g##z, h11, Cc##g##z)); \
        float u3 = fmaf(A##g##w, h10, fmaf(Bq##g##w, h11, Cc##g##w)); \
        u0 = __builtin_amdgcn_fmed3f(u0, 0.0f, THI); \
        u1 = __builtin_amdgcn_fmed3f(u1, 0.0f, THI); \
        u2 = __builtin_amdgcn_fmed3f(u2, 0.0f, THI); \
        u3 = __builtin_amdgcn_fmed3f(u3, 0.0f, THI); \
        const float f0 = ffract(u0), f1 = ffract(u1); \
        const float f2 = ffract(u2), f3 = ffract(u3); \
        const int i0 = (int)u0, i1 = (int)u1, i2r = (int)u2, i3 = (int)u3; \
        const float2 e0 = stab[i0], e1 = stab[i1], e2 = stab[i2r], e3 = stab[i3]; \
        a0 = fmaf(fmaf(e0.y, f0, e0.x), d4.x, a0); \
        a1 = fmaf(fmaf(e1.y, f1, e1.x), d4.y, a1); \
        a2 = fmaf(fmaf(e2.y, f2, e2.x), d4.z, a2); \
        a3 = fmaf(fmaf(e3.y, f3, e3.x), d4.w, a3); }
        REP8(GRP)
        const float acc = (a0 + a1) + (a2 + a3);
        kprev = acc;
        kacc = fmaf(wgt, acc, kacc);
      }
    }
    z = fmaf(hst * (1.0f / 6.0f), kacc, z);
    zt[((size_t)b * Ln + (i + 1)) * Hn + lane] = tanh_fast(z);
  }
}

// ---------------------------------------------------------------------------
// Kernel 2: readout + hermite coeffs. One block per batch element.
// ---------------------------------------------------------------------------
#define SPX(l_, o_) (((l_) << 4) | (((o_) + (l_)) & 15))
#define SZX(l_, h_) (((l_) << 6) | (((h_) + (l_)) & 63))

__global__ __launch_bounds__(128, 2) void ncde_epilogue_kernel(
    const float* __restrict__ zt, const float* __restrict__ t,
    const float* __restrict__ W_read, const float* __restrict__ b_read,
    float* __restrict__ out)
{
  __shared__ float sW[Hn * On];
  __shared__ float sz[Ln * Hn];
  __shared__ float sp[Ln * On];
  __shared__ float st_[Ln];
  const int b = blockIdx.x;
  const int tid = threadIdx.x;

  for (int i2 = tid; i2 < Hn * On; i2 += 128) sW[i2] = W_read[i2];
  st_[tid] = t[tid];
  const float* zb = zt + (size_t)b * Ln * Hn;
#pragma unroll 1
  for (int r = 0; r < 16; ++r) {
    const int base = (r * 128 + tid) * 4;       // 8192 floats, float4-granular
    const float4 v = *(const float4*)(zb + base);
    const int l = base >> 6, h = base & 63;     // h multiple of 4, no row wrap
    sz[SZX(l, h + 0)] = v.x;
    sz[SZX(l, h + 1)] = v.y;
    sz[SZX(l, h + 2)] = v.z;
    sz[SZX(l, h + 3)] = v.w;
  }
  __syncthreads();

  // Readout: thread tid owns row l = tid, all 16 outputs in registers.
  float acc0[On];
#pragma unroll
  for (int o = 0; o < On; ++o) acc0[o] = b_read[o];
#pragma unroll 2
  for (int h = 0; h < Hn; ++h) {
    const float zv = sz[SZX(tid, h)];
#pragma unroll
    for (int o = 0; o < On; ++o) acc0[o] = fmaf(zv, sW[h * On + o], acc0[o]);
  }
  float* po = out + ((size_t)b * Ln + tid) * On;
#pragma unroll
  for (int o = 0; o < On; ++o) sp[SPX(tid, o)] = acc0[o];
#pragma unroll
  for (int o4 = 0; o4 < 4; ++o4) {
    float4 v = make_float4(acc0[4*o4], acc0[4*o4+1], acc0[4*o4+2], acc0[4*o4+3]);
    *(float4*)(po + 4 * o4) = v;
  }
  __syncthreads();

  // Hermite coefficients of pred_y: a = p_i, b = d0, 2c, 3d (per o).
  float* cbo = out + (size_t)Bn * Ln * On + (size_t)b * NIv * 64;
#pragma unroll 1
  for (int r = 0; r < 16; ++r) {
    const int item = r * 128 + tid;
    if (item < NIv * On) {
      const int i = item >> 4, o = item & 15;
      const float p0 = sp[SPX(i, o)], p1 = sp[SPX(i + 1, o)];
      const float rdt = frcpf(st_[i + 1] - st_[i]);
      const float si = (p1 - p0) * rdt;
      float d0;
      if (i == 0) d0 = si;
      else d0 = (p0 - sp[SPX(i - 1, o)]) * frcpf(st_[i] - st_[i - 1]);
      const float d1 = si;
      float* cc = cbo + (size_t)i * 64 + o;
      cc[0]  = p0;
      cc[16] = d0;
      cc[32] = 2.0f * (3.0f * si - 2.0f * d0 - d1) * rdt;
      cc[48] = 3.0f * (d0 + d1 - 2.0f * si) * (rdt * rdt);
    }
  }
}

extern "C" void kernel_launch(void* const* d_in, const int* in_sizes, int n_in,
                              void* d_out, int out_size, void* d_ws, size_t ws_size,
                              hipStream_t stream) {
  const float* coeffs = (const float*)d_in[0];
  const float* t      = (const float*)d_in[1];
  const float* W_init = (const float*)d_in[2];
  const float* b_init = (const float*)d_in[3];
  const float* W1     = (const float*)d_in[4];
  const float* b1     = (const float*)d_in[5];
  const float* W2     = (const float*)d_in[6];
  const float* b2     = (const float*)d_in[7];
  const float* W_read = (const float*)d_in[8];
  const float* b_read = (const float*)d_in[9];
  float* out = (float*)d_out;
  float* zt  = (float*)d_ws;   // needs B*L*H*4 = 64 MiB of scratch

  ncde_scan_kernel<<<dim3(Bn / 4), dim3(256), 0, stream>>>(
      coeffs, t, W_init, b_init, W1, b1, W2, b2, zt);
  ncde_epilogue_kernel<<<dim3(Bn), dim3(128), 0, stream>>>(
      zt, t, W_read, b_read, out);
}

// Round 5
// 1654.218 us; speedup vs baseline: 1.0047x; 1.0047x over previous
//
#include <hip/hip_runtime.h>
#include <cstdint>
#include <cstddef>

// Problem constants (fixed by the reference).
constexpr int Bn = 2048, Ln = 128, Cn = 32, Hn = 64, On = 16;
constexpr int NIv = Ln - 1;                       // 127 intervals
constexpr float K2 = 2.885390081777927f;          // 2*log2(e): tanh(x)=1-2/(1+exp2(K2*x))

__device__ __forceinline__ float fexp2(float x) {
#if __has_builtin(__builtin_amdgcn_exp2f)
  return __builtin_amdgcn_exp2f(x);
#else
  float r; asm("v_exp_f32 %0, %1" : "=v"(r) : "v"(x)); return r;
#endif
}
__device__ __forceinline__ float frcpf(float x) {
#if __has_builtin(__builtin_amdgcn_rcpf)
  return __builtin_amdgcn_rcpf(x);
#else
  float r; asm("v_rcp_f32 %0, %1" : "=v"(r) : "v"(x)); return r;
#endif
}
__device__ __forceinline__ float tanh_fast(float x) {
  float e = fexp2(K2 * x);
  return fmaf(-2.0f, frcpf(e + 1.0f), 1.0f);
}

// One DPP add step of a butterfly reduce (full-rate VALU, no LDS).
template<int CTRL>
__device__ __forceinline__ float dpp_addstep(float p) {
  int q = __builtin_amdgcn_update_dpp(0, __float_as_int(p), CTRL, 0xF, 0xF, true);
  return p + __int_as_float(q);
}
// After these 4 steps every 16-lane row holds its row-sum in all lanes.
__device__ __forceinline__ float dpp_rowsum16(float p) {
  p = dpp_addstep<0xB1>(p);    // quad_perm [1,0,3,2]  (xor1)
  p = dpp_addstep<0x4E>(p);    // quad_perm [2,3,0,1]  (xor2)
  p = dpp_addstep<0x141>(p);   // row_half_mirror      (xor4..7)
  p = dpp_addstep<0x140>(p);   // row_mirror           (xor8..15)
  return p;
}
__device__ __forceinline__ float lane4_total(float p) {
  float s0 = __int_as_float(__builtin_amdgcn_readlane(__float_as_int(p), 0));
  float s1 = __int_as_float(__builtin_amdgcn_readlane(__float_as_int(p), 16));
  float s2 = __int_as_float(__builtin_amdgcn_readlane(__float_as_int(p), 32));
  float s3 = __int_as_float(__builtin_amdgcn_readlane(__float_as_int(p), 48));
  return (s0 + s1) + (s2 + s3);
}

// ---------------------------------------------------------------------------
// Kernel 1: sequential RK4 scan, C-SPLIT across 2 waves per batch element.
// Block = 256 threads = 4 waves = 2 batch elements; wave `half` owns 16 of
// the 32 channels -> 4096 waves total (4/SIMD, double round-3's occupancy).
// Weights live in LDS [c][h] (conflict-free, compile-time ds offsets) —
// ends the 3-round register-residency fight. tanh = exp2 + rcp (round-3
// math; LUT reverted: 9.5e7 bank conflicts, more issue slots).
// Per stage: partial acc over 16 c's -> LDS exchange (1 barrier) -> both
// waves reconstruct identical full acc (bitwise: one commutative add).
// ---------------------------------------------------------------------------
__global__ __launch_bounds__(256, 4) void ncde_scan_kernel(
    const float* __restrict__ coeffs, const float* __restrict__ t,
    const float* __restrict__ W_init, const float* __restrict__ b_init,
    const float* __restrict__ W1, const float* __restrict__ b1,
    const float* __restrict__ W2, const float* __restrict__ b2,
    float* __restrict__ zt)
{
  __shared__ float2 sw[Cn * Hn];               // [c][h] = (K2*w20, K2*w21) 16 KB
  __shared__ float  scc[Cn * Hn];              // [c][h] = K2*b2             8 KB
  __shared__ alignas(16) float sdx[2][5][Cn];  // [batch-slot][s-index][c]
  __shared__ float  sacc[2][2][Hn];            // [batch-slot][half][lane]
  const int tid  = threadIdx.x;
  const int lane = tid & 63;
  const int wv   = tid >> 6;          // 0..3
  const int bi   = wv >> 1;           // batch slot in block
  const int half = wv & 1;            // which 16 channels
  const int b    = (blockIdx.x << 1) | bi;

  // Stage weights into LDS, [c][h] layout, pre-scaled by K2 (once).
  for (int e = tid; e < Cn * Hn; e += 256) {
    const int h = e >> 5, c = e & 31;
    sw [c * Hn + h] = make_float2(K2 * W2[h * 32 + c], K2 * W2[2048 + h * 32 + c]);
    scc[c * Hn + h] = K2 * b2[h * 32 + c];
  }

  const float w10 = W1[2 * lane], w11 = W1[2 * lane + 1];
  const float sb0 = b1[0], sb1 = b1[1];

  // z0 = X0 @ W_init + b_init, X0 = a-part of interval 0.
  const float* cb0 = coeffs + (size_t)b * NIv * 128;
  if (half == 0 && lane < 32) sdx[bi][0][lane] = cb0[lane];
  __syncthreads();                    // weights + a-vector staged
  float z = b_init[lane];
#pragma unroll 4
  for (int c = 0; c < 32; ++c)
    z = fmaf(sdx[bi][0][c], W_init[(c << 6) + lane], z);
  if (half == 0) zt[(size_t)b * Ln * Hn + lane] = tanh_fast(z);
  __syncthreads();                    // z0 reads done before interval-0 sdx writes

  // Per-lane LDS pointers for this wave's c-half (all hot offsets literal).
  const float2* swp  = sw  + (half << 4) * Hn + lane;    // swp[cc*Hn]
  const float*  sccp = scc + (half << 4) * Hn + lane;    // sccp[cc*Hn]
  float* const saccw       = &sacc[bi][half][lane];
  const float* const saccr = &sacc[bi][half ^ 1][lane];

#pragma unroll 1
  for (int i = 0; i < NIv; ++i) {
    const float* cb = cb0 + (size_t)i * 128;
    const float dti = t[i + 1] - t[i];
    const float hst = 0.5f * dti;
    // 5 distinct dXdt vectors (s = 0,.25,.5,.75,1 × dti); half 0 writes
    // k=0..2, half 1 writes k=3..4. All interval-(i-1) dx reads were
    // separated from these writes by the last stage's barrier.
    if (lane < 32) {
      const float bv = cb[32 + lane];
      const float cv = cb[64 + lane];
      const float dv = cb[96 + lane];
      const float q = 0.25f * dti;
      if (half == 0) {
#pragma unroll
        for (int k = 0; k < 3; ++k) {
          const float s = q * (float)k;
          sdx[bi][k][lane] = fmaf(fmaf(dv, s, cv), s, bv);
        }
      } else {
#pragma unroll
        for (int k = 3; k < 5; ++k) {
          const float s = q * (float)k;
          sdx[bi][k][lane] = fmaf(fmaf(dv, s, cv), s, bv);
        }
      }
    }
    __syncthreads();

    float kacc = 0.0f, kprev = 0.0f;
#pragma unroll
    for (int j = 0; j < 2; ++j) {          // N_SUB substeps
      if (j == 1) { z = fmaf(hst * (1.0f / 6.0f), kacc, z); kacc = 0.0f; kprev = 0.0f; }
#pragma unroll
      for (int st = 0; st < 4; ++st) {     // RK4 stages
        const float cin = (st == 0) ? 0.0f : (st == 3) ? hst : 0.5f * hst;
        const float wgt = (st == 1 || st == 2) ? 2.0f : 1.0f;
        const int kidx = 2 * j + ((st + 1) >> 1);          // compile-time 0..4
        const float* dxp = &sdx[bi][kidx][half << 4];
        const float zs = fmaf(cin, kprev, z);
        // h1 = relu(zs @ W1 + b1): DPP butterfly (identical in both waves).
        const float p0 = dpp_rowsum16(zs * w10);
        const float p1 = dpp_rowsum16(zs * w11);
        const float h10 = fmaxf(lane4_total(p0) + sb0, 0.0f);
        const float h11 = fmaxf(lane4_total(p1) + sb1, 0.0f);
        float a0 = 0.0f, a1 = 0.0f, a2 = 0.0f, a3 = 0.0f;
#pragma unroll
        for (int g = 0; g < 4; ++g) {      // 16 channels, 4 per group
          const float4 d4 = *(const float4*)(dxp + 4 * g);
          {
            const float2 w = swp[(4 * g + 0) * Hn];
            const float u = fmaf(w.x, h10, fmaf(w.y, h11, sccp[(4 * g + 0) * Hn]));
            const float r = frcpf(fexp2(u) + 1.0f);
            a0 = fmaf(fmaf(-2.0f, r, 1.0f), d4.x, a0);
          }
          {
            const float2 w = swp[(4 * g + 1) * Hn];
            const float u = fmaf(w.x, h10, fmaf(w.y, h11, sccp[(4 * g + 1) * Hn]));
            const float r = frcpf(fexp2(u) + 1.0f);
            a1 = fmaf(fmaf(-2.0f, r, 1.0f), d4.y, a1);
          }
          {
            const float2 w = swp[(4 * g + 2) * Hn];
            const float u = fmaf(w.x, h10, fmaf(w.y, h11, sccp[(4 * g + 2) * Hn]));
            const float r = frcpf(fexp2(u) + 1.0f);
            a2 = fmaf(fmaf(-2.0f, r, 1.0f), d4.z, a2);
          }
          {
            const float2 w = swp[(4 * g + 3) * Hn];
            const float u = fmaf(w.x, h10, fmaf(w.y, h11, sccp[(4 * g + 3) * Hn]));
            const float r = frcpf(fexp2(u) + 1.0f);
            a3 = fmaf(fmaf(-2.0f, r, 1.0f), d4.w, a3);
          }
        }
        const float part = (a0 + a1) + (a2 + a3);
        *saccw = part;
        __syncthreads();
        const float acc = part + *saccr;   // commutative: bitwise-identical in both waves
        kprev = acc;
        kacc = fmaf(wgt, acc, kacc);
      }
    }
    z = fmaf(hst * (1.0f / 6.0f), kacc, z);
    if (half == 0) zt[((size_t)b * Ln + (i + 1)) * Hn + lane] = tanh_fast(z);
  }
}

// ---------------------------------------------------------------------------
// Kernel 2: readout + hermite coeffs. One block per batch element.
// ---------------------------------------------------------------------------
#define SPX(l_, o_) (((l_) << 4) | (((o_) + (l_)) & 15))
#define SZX(l_, h_) (((l_) << 6) | (((h_) + (l_)) & 63))

__global__ __launch_bounds__(128, 2) void ncde_epilogue_kernel(
    const float* __restrict__ zt, const float* __restrict__ t,
    const float* __restrict__ W_read, const float* __restrict__ b_read,
    float* __restrict__ out)
{
  __shared__ float sW[Hn * On];
  __shared__ float sz[Ln * Hn];
  __shared__ float sp[Ln * On];
  __shared__ float st_[Ln];
  const int b = blockIdx.x;
  const int tid = threadIdx.x;

  for (int i2 = tid; i2 < Hn * On; i2 += 128) sW[i2] = W_read[i2];
  st_[tid] = t[tid];
  const float* zb = zt + (size_t)b * Ln * Hn;
#pragma unroll 1
  for (int r = 0; r < 16; ++r) {
    const int base = (r * 128 + tid) * 4;       // 8192 floats, float4-granular
    const float4 v = *(const float4*)(zb + base);
    const int l = base >> 6, h = base & 63;     // h multiple of 4, no row wrap
    sz[SZX(l, h + 0)] = v.x;
    sz[SZX(l, h + 1)] = v.y;
    sz[SZX(l, h + 2)] = v.z;
    sz[SZX(l, h + 3)] = v.w;
  }
  __syncthreads();

  // Readout: thread tid owns row l = tid, all 16 outputs in registers.
  float acc0[On];
#pragma unroll
  for (int o = 0; o < On; ++o) acc0[o] = b_read[o];
#pragma unroll 2
  for (int h = 0; h < Hn; ++h) {
    const float zv = sz[SZX(tid, h)];
#pragma unroll
    for (int o = 0; o < On; ++o) acc0[o] = fmaf(zv, sW[h * On + o], acc0[o]);
  }
  float* po = out + ((size_t)b * Ln + tid) * On;
#pragma unroll
  for (int o = 0; o < On; ++o) sp[SPX(tid, o)] = acc0[o];
#pragma unroll
  for (int o4 = 0; o4 < 4; ++o4) {
    float4 v = make_float4(acc0[4*o4], acc0[4*o4+1], acc0[4*o4+2], acc0[4*o4+3]);
    *(float4*)(po + 4 * o4) = v;
  }
  __syncthreads();

  // Hermite coefficients of pred_y: a = p_i, b = d0, 2c, 3d (per o).
  float* cbo = out + (size_t)Bn * Ln * On + (size_t)b * NIv * 64;
#pragma unroll 1
  for (int r = 0; r < 16; ++r) {
    const int item = r * 128 + tid;
    if (item < NIv * On) {
      const int i = item >> 4, o = item & 15;
      const float p0 = sp[SPX(i, o)], p1 = sp[SPX(i + 1, o)];
      const float rdt = frcpf(st_[i + 1] - st_[i]);
      const float si = (p1 - p0) * rdt;
      float d0;
      if (i == 0) d0 = si;
      else d0 = (p0 - sp[SPX(i - 1, o)]) * frcpf(st_[i] - st_[i - 1]);
      const float d1 = si;
      float* cc = cbo + (size_t)i * 64 + o;
      cc[0]  = p0;
      cc[16] = d0;
      cc[32] = 2.0f * (3.0f * si - 2.0f * d0 - d1) * rdt;
      cc[48] = 3.0f * (d0 + d1 - 2.0f * si) * (rdt * rdt);
    }
  }
}

extern "C" void kernel_launch(void* const* d_in, const int* in_sizes, int n_in,
                              void* d_out, int out_size, void* d_ws, size_t ws_size,
                              hipStream_t stream) {
  const float* coeffs = (const float*)d_in[0];
  const float* t      = (const float*)d_in[1];
  const float* W_init = (const float*)d_in[2];
  const float* b_init = (const float*)d_in[3];
  const float* W1     = (const float*)d_in[4];
  const float* b1     = (const float*)d_in[5];
  const float* W2     = (const float*)d_in[6];
  const float* b2     = (const float*)d_in[7];
  const float* W_read = (const float*)d_in[8];
  const float* b_read = (const float*)d_in[9];
  float* out = (float*)d_out;
  float* zt  = (float*)d_ws;   // needs B*L*H*4 = 64 MiB of scratch

  ncde_scan_kernel<<<dim3(Bn / 2), dim3(256), 0, stream>>>(
      coeffs, t, W_init, b_init, W1, b1, W2, b2, zt);
  ncde_epilogue_kernel<<<dim3(Bn), dim3(128), 0, stream>>>(
      zt, t, W_read, b_read, out);
}